// Round 6
// baseline (116.111 us; speedup 1.0000x reference)
//
#include <hip/hip_runtime.h>

// x [N=8, C=64, D=16, H=128, W=128] f32, bias [64] f32.
// out = tanh(softmax_C(mean_D(x) + bias)) * 2, f32 [N,C,H,W].
//
// Fused-LDS v3: same STILE=256 tile as round 5 but 1024-thread blocks ->
// 2 blocks/CU x 16 waves = 32 waves/CU (8/SIMD, HW max) instead of 16.
// Round-5 was latency-bound at 4 waves/SIMD (5.1 TB/s of ~6.5 ceiling).
// __launch_bounds__(1024, 8) pins VGPR budget to 64; per-thread state is
// deliberately small (4ch x 16d, 2 float4 accumulators).
constexpr int C     = 64;
constexpr int D     = 16;
constexpr int HW    = 128 * 128;
constexpr int HW4   = HW / 4;
constexpr int STILE = 256;
constexpr float SCALING = 2.0f;

__global__ __launch_bounds__(1024, 8) void fused_lds_v3(
    const float* __restrict__ x,
    const float* __restrict__ bias,
    float* __restrict__ out)
{
    __shared__ float  logit[C][STILE];   // 64 KB
    __shared__ float2 red[8][128];       // 8 KB  (reused: max, then sum)

    const int b      = blockIdx.x;
    const int n      = b >> 6;           // HW/STILE = 64 tiles per image
    const int s_base = (b & 63) * STILE;

    // ---------- Phase 1: mean over depth ----------
    // thread = (g: 4 channels) x (q: one float4 slot). Wave lanes q=0..63 ->
    // 64 consecutive float4 = 1KB contiguous per (c,d) load instruction.
    const int q = threadIdx.x & 63;
    const int g = threadIdx.x >> 6;      // 0..15, wave-uniform

    for (int k = 0; k < 4; ++k) {
        const int c = g * 4 + k;
        const float4* p =
            (const float4*)(x + ((size_t)(n * C + c) * D) * HW + s_base) + q;
        float4 a0 = {0, 0, 0, 0}, a1 = a0;
        #pragma unroll
        for (int d = 0; d < D; d += 2) {
            float4 v0 = p[(size_t)(d + 0) * HW4];
            float4 v1 = p[(size_t)(d + 1) * HW4];
            a0.x += v0.x; a0.y += v0.y; a0.z += v0.z; a0.w += v0.w;
            a1.x += v1.x; a1.y += v1.y; a1.z += v1.z; a1.w += v1.w;
        }
        const float bc = bias[c];
        float4 r;
        r.x = (a0.x + a1.x) * (1.0f / D) + bc;
        r.y = (a0.y + a1.y) * (1.0f / D) + bc;
        r.z = (a0.z + a1.z) * (1.0f / D) + bc;
        r.w = (a0.w + a1.w) * (1.0f / D) + bc;
        *(float4*)&logit[c][4 * q] = r;
    }
    __syncthreads();

    // ---------- Phase 2: softmax over C + tanh ----------
    // thread = (slot: s-pair, float2) x (h: 8 channels). All LDS traffic is
    // 512B-contiguous per wave (conflict-free); global stores 8B/lane.
    const int slot = threadIdx.x & 127;
    const int h    = threadIdx.x >> 7;   // 0..7, wave-pair-uniform
    const int c0   = h * 8;

    float2 pm = {-INFINITY, -INFINITY};
    #pragma unroll
    for (int k = 0; k < 8; ++k) {
        float2 v = *(const float2*)&logit[c0 + k][2 * slot];
        pm.x = fmaxf(pm.x, v.x); pm.y = fmaxf(pm.y, v.y);
    }
    red[h][slot] = pm;
    __syncthreads();

    float2 m2 = red[0][slot];
    #pragma unroll
    for (int j = 1; j < 8; ++j) {
        float2 v = red[j][slot];
        m2.x = fmaxf(m2.x, v.x); m2.y = fmaxf(m2.y, v.y);
    }
    __syncthreads();                     // max reads done before sum overwrite

    float2 ps = {0.f, 0.f};
    #pragma unroll
    for (int k = 0; k < 8; ++k) {
        float2* lp = (float2*)&logit[c0 + k][2 * slot];
        float2 v = *lp;
        v.x = __expf(v.x - m2.x);
        v.y = __expf(v.y - m2.y);
        *lp = v;                         // slot owned by this thread
        ps.x += v.x; ps.y += v.y;
    }
    red[h][slot] = ps;
    __syncthreads();

    float2 tot = red[0][slot];
    #pragma unroll
    for (int j = 1; j < 8; ++j) {
        float2 v = red[j][slot];
        tot.x += v.x; tot.y += v.y;
    }
    const float invx = 1.0f / tot.x, invy = 1.0f / tot.y;

    float* po = out + (size_t)(n * C + c0) * HW + s_base + 2 * slot;
    #pragma unroll
    for (int k = 0; k < 8; ++k) {
        float2 v = *(const float2*)&logit[c0 + k][2 * slot];
        const float px_ = v.x * invx, py_ = v.y * invy;   // in (0, 1]
        const float ex = __expf(2.0f * px_);              // tanh via exp
        const float ey = __expf(2.0f * py_);
        float2 r;
        r.x = SCALING * (1.0f - 2.0f / (ex + 1.0f));
        r.y = SCALING * (1.0f - 2.0f / (ey + 1.0f));
        *(float2*)(po + (size_t)k * HW) = r;
    }
}

extern "C" void kernel_launch(void* const* d_in, const int* in_sizes, int n_in,
                              void* d_out, int out_size, void* d_ws, size_t ws_size,
                              hipStream_t stream)
{
    const float* x    = (const float*)d_in[0];
    const float* bias = (const float*)d_in[1];
    float* out        = (float*)d_out;

    const int N      = in_sizes[0] / (C * D * HW);   // = 8
    const int blocks = N * (HW / STILE);             // 512
    fused_lds_v3<<<blocks, 1024, 0, stream>>>(x, bias, out);
}